// Round 3
// baseline (94052.747 us; speedup 1.0000x reference)
//
#include <hip/hip_runtime.h>
#include <hip/hip_bf16.h>

#define BB 4
#define CC 192
#define LL 65536
#define WWW 256
#define HID 768

__device__ __forceinline__ float us2f(unsigned short u) { return __uint_as_float(((unsigned int)u) << 16); }
__device__ __forceinline__ unsigned short f2us(float f) {
    // round-to-nearest-even bf16 truncation
    unsigned int x = __float_as_uint(f);
    unsigned int r = (x + 0x7FFFu + ((x >> 16) & 1u)) >> 16;
    return (unsigned short)r;
}

__device__ __forceinline__ float gelu_exact(float x) {
    return 0.5f * x * (1.0f + erff(x * 0.70710678118654752440f));
}

__device__ __forceinline__ float dot8(const float4 a, const float4 b, const float4 wa, const float4 wb) {
    return a.x*wa.x + a.y*wa.y + a.z*wa.z + a.w*wa.w
         + b.x*wb.x + b.y*wb.y + b.z*wb.z + b.w*wb.w;
}

// ---------------- Kernel A: gather window + LN1 + QKV + attn + proj + residual ----------------
// Reads x in native (B,C,L) f32 layout, writes xt2 = shortcut + attn_out, also (B,C,L) f32, into d_out.
__global__ __launch_bounds__(256) void kA(
    const float* __restrict__ x, const int* __restrict__ perm,
    const float* __restrict__ n1g, const float* __restrict__ n1b,
    const float* __restrict__ qkvw, const float* __restrict__ qkvb,
    const float* __restrict__ projw, const float* __restrict__ projb,
    float* __restrict__ xt2)
{
    __shared__ float s_h[16][CC];              // raw -> LN'd -> (reused) o
    __shared__ float s_qkv[16][3*CC];          // q|k|v per token
    __shared__ float s_attn[96][16];           // 6 heads * 16 rows
    __shared__ unsigned short s_stash[16][CC]; // bf16 copy of raw x for residual
    __shared__ float s_mu[16], s_rs[16];
    __shared__ int s_tok[16];

    const int tid = threadIdx.x;
    const int wid = blockIdx.x;
    const int b  = wid >> 12;        // 4096 windows per batch
    const int hb = (wid >> 6) & 63;
    const int wb = wid & 63;

    if (tid < 16) {
        int si = tid >> 2, sj = tid & 3;
        s_tok[tid] = perm[(hb * 4 + si) * WWW + wb * 4 + sj];
    }
    __syncthreads();

    // gather raw x (scattered: stride-L per channel)
    for (int idx = tid; idx < 16 * CC; idx += 256) {
        int n = idx / CC, c = idx - n * CC;
        float v = x[((size_t)b * CC + c) * LL + s_tok[n]];
        s_h[n][c] = v;
        s_stash[n][c] = f2us(v);
    }
    __syncthreads();

    // LN stats: 16 threads, one token each
    if (tid < 16) {
        float s = 0.f, q = 0.f;
        for (int c = 0; c < CC; c++) { float v = s_h[tid][c]; s += v; q += v * v; }
        float mu = s * (1.f / CC);
        float var = q * (1.f / CC) - mu * mu;
        s_mu[tid] = mu;
        s_rs[tid] = rsqrtf(var + 1e-5f);
    }
    __syncthreads();

    // normalize in place
    for (int idx = tid; idx < 16 * CC; idx += 256) {
        int n = idx / CC, c = idx - n * CC;
        s_h[n][c] = (s_h[n][c] - s_mu[n]) * s_rs[n] * n1g[c] + n1b[c];
    }
    __syncthreads();

    // qkv = h @ qkv_w^T + qkv_b
    for (int oc = tid; oc < 3 * CC; oc += 256) {
        float acc[16];
        for (int i = 0; i < 16; i++) acc[i] = 0.f;
        const float4* wr = (const float4*)(qkvw + (size_t)oc * CC);
        for (int k8 = 0; k8 < CC / 8; ++k8) {
            float4 wa = wr[k8 * 2], wb2 = wr[k8 * 2 + 1];
            for (int n = 0; n < 16; n++) {
                const float4* hp = (const float4*)(&s_h[n][k8 * 8]);
                acc[n] += dot8(hp[0], hp[1], wa, wb2);
            }
        }
        float bias = qkvb[oc];
        for (int n = 0; n < 16; n++) s_qkv[n][oc] = acc[n] + bias;
    }
    __syncthreads();

    // scores = SCALE * q @ k^T   (6 heads x 16 x 16)
    for (int idx = tid; idx < 1536; idx += 256) {
        int head = idx >> 8, r = (idx >> 4) & 15, col = idx & 15;
        float s = 0.f;
        for (int d = 0; d < 32; d++)
            s += s_qkv[r][head * 32 + d] * s_qkv[col][CC + head * 32 + d];
        s_attn[head * 16 + r][col] = s * 4.0f;
    }
    __syncthreads();

    // softmax over 16 keys
    if (tid < 96) {
        float mx = -1e30f;
        for (int i = 0; i < 16; i++) mx = fmaxf(mx, s_attn[tid][i]);
        float ss = 0.f;
        for (int i = 0; i < 16; i++) { float e = __expf(s_attn[tid][i] - mx); ss += e; s_attn[tid][i] = e; }
        float inv = 1.f / ss;
        for (int i = 0; i < 16; i++) s_attn[tid][i] *= inv;
    }
    __syncthreads();

    // o = attn @ v  (into s_h, reuse)
    for (int idx = tid; idx < 16 * CC; idx += 256) {
        int n = idx / CC, c = idx - n * CC;
        int head = c >> 5;
        float s = 0.f;
        for (int m = 0; m < 16; m++) s += s_attn[head * 16 + n][m] * s_qkv[m][2 * CC + c];
        s_h[n][c] = s;
    }
    __syncthreads();

    // proj + residual, scatter to (B,C,L)
    if (tid < CC) {
        const int c = tid;
        float acc[16];
        for (int i = 0; i < 16; i++) acc[i] = 0.f;
        const float4* wr = (const float4*)(projw + (size_t)c * CC);
        for (int k8 = 0; k8 < CC / 8; ++k8) {
            float4 wa = wr[k8 * 2], wb2 = wr[k8 * 2 + 1];
            for (int n = 0; n < 16; n++) {
                const float4* hp = (const float4*)(&s_h[n][k8 * 8]);
                acc[n] += dot8(hp[0], hp[1], wa, wb2);
            }
        }
        float bias = projb[c];
        for (int n = 0; n < 16; n++) {
            float res = us2f(s_stash[n][c]);
            xt2[((size_t)b * CC + c) * LL + s_tok[n]] = acc[n] + bias + res;
        }
    }
}

// ---------------- Kernel B: LN2 + MLP + residual, in-place on (B,C,L) ----------------
// Block handles 16 consecutive tokens (same b). Only touches its own addresses -> no aliasing.
__global__ __launch_bounds__(256) void kB(
    float* __restrict__ xt2,
    const float* __restrict__ n2g, const float* __restrict__ n2b,
    const float* __restrict__ fc1w, const float* __restrict__ fc1b,
    const float* __restrict__ fc2w, const float* __restrict__ fc2b)
{
    __shared__ float s_x[16][CC];      // raw -> LN'd
    __shared__ float s_a[16][HID];     // gelu(fc1) activations
    __shared__ float s_mu[16], s_rs[16];

    const int tid = threadIdx.x;
    const int t0 = blockIdx.x * 16;    // 16 consecutive tokens, same b
    const int b  = t0 >> 16;           // / LL
    const int l0 = t0 & (LL - 1);

    for (int idx = tid; idx < 16 * CC; idx += 256) {
        int n = idx / CC, c = idx - n * CC;
        s_x[n][c] = xt2[((size_t)b * CC + c) * LL + l0 + n];
    }
    __syncthreads();

    if (tid < 16) {
        float s = 0.f, q = 0.f;
        for (int c = 0; c < CC; c++) { float v = s_x[tid][c]; s += v; q += v * v; }
        float mu = s * (1.f / CC);
        float var = q * (1.f / CC) - mu * mu;
        s_mu[tid] = mu;
        s_rs[tid] = rsqrtf(var + 1e-5f);
    }
    __syncthreads();

    for (int idx = tid; idx < 16 * CC; idx += 256) {
        int n = idx / CC, c = idx - n * CC;
        s_x[n][c] = (s_x[n][c] - s_mu[n]) * s_rs[n] * n2g[c] + n2b[c];
    }
    __syncthreads();

    // fc1 + exact gelu: thread owns oc = tid, tid+256, tid+512
    for (int pass = 0; pass < 3; pass++) {
        int oc = tid + pass * 256;
        float acc[16];
        for (int i = 0; i < 16; i++) acc[i] = 0.f;
        const float4* wr = (const float4*)(fc1w + (size_t)oc * CC);
        for (int k8 = 0; k8 < CC / 8; ++k8) {
            float4 wa = wr[k8 * 2], wb2 = wr[k8 * 2 + 1];
            for (int n = 0; n < 16; n++) {
                const float4* xp = (const float4*)(&s_x[n][k8 * 8]);
                acc[n] += dot8(xp[0], xp[1], wa, wb2);
            }
        }
        float bias = fc1b[oc];
        for (int n = 0; n < 16; n++) s_a[n][oc] = gelu_exact(acc[n] + bias);
    }
    __syncthreads();

    // fc2 + residual, in-place store (re-read own addresses for residual)
    if (tid < CC) {
        const int c = tid;
        float acc[16];
        for (int i = 0; i < 16; i++) acc[i] = 0.f;
        const float4* wr = (const float4*)(fc2w + (size_t)c * HID);
        for (int k8 = 0; k8 < HID / 8; ++k8) {
            float4 wa = wr[k8 * 2], wb2 = wr[k8 * 2 + 1];
            for (int n = 0; n < 16; n++) {
                const float4* ap = (const float4*)(&s_a[n][k8 * 8]);
                acc[n] += dot8(ap[0], ap[1], wa, wb2);
            }
        }
        float bias = fc2b[c];
        for (int n = 0; n < 16; n++) {
            size_t addr = ((size_t)b * CC + c) * LL + l0 + n;
            float res = xt2[addr];
            xt2[addr] = acc[n] + bias + res;
        }
    }
}

extern "C" void kernel_launch(void* const* d_in, const int* in_sizes, int n_in,
                              void* d_out, int out_size, void* d_ws, size_t ws_size,
                              hipStream_t stream) {
    const float* x     = (const float*)d_in[0];
    const int*   perm  = (const int*)d_in[1];
    const float* n1g   = (const float*)d_in[2];
    const float* n1b   = (const float*)d_in[3];
    const float* qkvw  = (const float*)d_in[4];
    const float* qkvb  = (const float*)d_in[5];
    const float* projw = (const float*)d_in[6];
    const float* projb = (const float*)d_in[7];
    const float* n2g   = (const float*)d_in[8];
    const float* n2b   = (const float*)d_in[9];
    const float* fc1w  = (const float*)d_in[10];
    const float* fc1b  = (const float*)d_in[11];
    const float* fc2w  = (const float*)d_in[12];
    const float* fc2b  = (const float*)d_in[13];

    float* out = (float*)d_out;   // (B,C,L) xt2 scratch, then final output (same layout)

    kA<<<16384, 256, 0, stream>>>(x, perm, n1g, n1b, qkvw, qkvb, projw, projb, out);
    kB<<<16384, 256, 0, stream>>>(out, n2g, n2b, fc1w, fc1b, fc2w, fc2b);
    (void)d_ws; (void)ws_size; (void)in_sizes; (void)n_in;
}